// Round 7
// baseline (589.032 us; speedup 1.0000x reference)
//
#include <hip/hip_runtime.h>
#include <math.h>

#define NN 50000
#define NE 800000
#define NG 64
#define D 128
#define IMG 4096
#define NT 30
#define SCAN_BLOCKS ((NN + 255) / 256)

typedef unsigned int uint;
typedef unsigned short ushort;
typedef __attribute__((ext_vector_type(8))) __bf16 bf16x8;
typedef __attribute__((ext_vector_type(4))) float f32x4;

// bf16 helpers (bit-level, RNE pack / shift unpack)
__device__ __forceinline__ uint bf16rne(float f) {
  uint h = __float_as_uint(f);
  return (h + 0x7fffu + ((h >> 16) & 1u)) >> 16;
}
__device__ __forceinline__ uint pack2bf(float a, float b) {
  return bf16rne(a) | (bf16rne(b) << 16);
}
__device__ __forceinline__ float bflo(uint u) { return __uint_as_float(u << 16); }
__device__ __forceinline__ float bfhi(uint u) { return __uint_as_float(u & 0xffff0000u); }

// X/xw bf16 storage is SLAB-MAJOR: slab s (s=0..3) holds uints [NN][16]
// covering feature cols 32s..32s+31. Slab = 3.2 MB -> fits per-XCD L2.

// ---------------- graph preprocessing ----------------

__global__ void edge_slot(const int* __restrict__ col, int* __restrict__ cnt,
                          int* __restrict__ slot) {
  int e = blockIdx.x * 256 + threadIdx.x;
  if (e < NE) {
    int c = col[e];
    slot[e] = atomicAdd(&cnt[c], 1);
  }
}

__global__ __launch_bounds__(256) void scan_blocks(const int* __restrict__ cnt,
                                                   int* __restrict__ incl,
                                                   int* __restrict__ partial) {
  __shared__ int sd[256];
  int t = threadIdx.x;
  int i = blockIdx.x * 256 + t;
  int v = (i < NN) ? cnt[i] : 0;
  sd[t] = v;
  __syncthreads();
  #pragma unroll
  for (int s = 1; s < 256; s <<= 1) {
    int add = (t >= s) ? sd[t - s] : 0;
    __syncthreads();
    sd[t] += add;
    __syncthreads();
  }
  if (i < NN) incl[i] = sd[t];
  if (t == 255) partial[blockIdx.x] = sd[255];
}

__global__ __launch_bounds__(256) void scan_partials(int* __restrict__ partial, int nb) {
  __shared__ int sd[256];
  int t = threadIdx.x;
  int v = (t < nb) ? partial[t] : 0;
  sd[t] = v;
  __syncthreads();
  #pragma unroll
  for (int s = 1; s < 256; s <<= 1) {
    int add = (t >= s) ? sd[t - s] : 0;
    __syncthreads();
    sd[t] += add;
    __syncthreads();
  }
  if (t < nb) partial[t] = (t == 0) ? 0 : sd[t - 1];
}

__global__ __launch_bounds__(256) void scan_apply(const int* __restrict__ incl,
                                                  const int* __restrict__ partial,
                                                  int* __restrict__ off) {
  int i = blockIdx.x * 256 + threadIdx.x;
  if (i < NN) off[i + 1] = incl[i] + partial[blockIdx.x];
  if (i == 0) off[0] = 0;
}

__global__ void fill_scatter(const int* __restrict__ row, const int* __restrict__ col,
                             const float* __restrict__ ew, const int* __restrict__ off,
                             const int* __restrict__ slot, int* __restrict__ src_s,
                             float* __restrict__ ew_s) {
  int e = blockIdx.x * 256 + threadIdx.x;
  if (e < NE) {
    int idx = off[col[e]] + slot[e];
    src_s[idx] = row[e];
    ew_s[idx] = ew[e];
  }
}

__global__ void deg_csr(const int* __restrict__ off, const float* __restrict__ ew_s,
                        float* __restrict__ dis) {
  int i = blockIdx.x * 256 + threadIdx.x;
  if (i < NN) {
    int s = off[i], e = off[i + 1];
    float acc = 0.f;
    for (int j = s; j < e; j++) acc += ew_s[j];
    dis[i] = 1.0f / sqrtf(acc + 1.0f);
  }
}

__global__ void norm_fill(const int* __restrict__ off, const int* __restrict__ src_s,
                          const float* __restrict__ ew_s, const float* __restrict__ dis,
                          const int* __restrict__ types, float* __restrict__ norm_s,
                          int* __restrict__ styp_s) {
  int i = blockIdx.x * 256 + threadIdx.x;
  if (i < NN) {
    int s = off[i], e = off[i + 1];
    float dc = dis[i];
    for (int j = s; j < e; j++) {
      int sv = src_s[j];
      norm_s[j] = dis[sv] * ew_s[j] * dc;
      styp_s[j] = types[sv];
    }
  }
}

// embW[t][n] = sum_k emb[t][k] * W1[n][k]   (30 x 128)
__global__ void embw_k(const float* __restrict__ emb, const float* __restrict__ W,
                       float* __restrict__ embW) {
  int tid = blockIdx.x * 256 + threadIdx.x;
  if (tid < NT * D) {
    int t = tid >> 7, n = tid & 127;
    const float* e = emb + (size_t)t * D;
    const float* w = W + (size_t)n * D;
    float acc = 0.f;
    for (int k = 0; k < D; k += 4) {
      float4 ev = *(const float4*)(e + k);
      float4 wv = *(const float4*)(w + k);
      acc += ev.x * wv.x + ev.y * wv.y + ev.z * wv.z + ev.w * wv.w;
    }
    embW[tid] = acc;
  }
}

// fp32 W (128x128, row-major k-contig) -> bf16 packed (64 uints per row)
__global__ void convW(const float* __restrict__ W, uint* __restrict__ Wbf) {
  int idx = blockIdx.x * 256 + threadIdx.x;  // 128*64
  if (idx < D * 64) {
    float2 v = ((const float2*)W)[idx];
    Wbf[idx] = pack2bf(v.x, v.y);
  }
}

// ---------------- layer 1 fused: X1 = relu(C @ embW1 + b1), bf16 slab out ----------------

__global__ __launch_bounds__(256) void lay1_fused(const int* __restrict__ off,
                                                  const int* __restrict__ styp_s,
                                                  const float* __restrict__ norm_s,
                                                  const float* __restrict__ dis,
                                                  const int* __restrict__ types,
                                                  const float* __restrict__ embW,
                                                  const float* __restrict__ b1,
                                                  uint* __restrict__ outbf) {
  __shared__ float sE[NT * D];
  __shared__ float sC[16][32];
  __shared__ float sB[D];
  int t = threadIdx.x;
  for (int i = t; i < NT * D; i += 256) sE[i] = embW[i];
  if (t < D) sB[t] = b1[t];
  for (int i = t; i < 16 * 32; i += 256) ((float*)sC)[i] = 0.f;
  __syncthreads();
  int wave = t >> 6, lane = t & 63;
  int nodebase = blockIdx.x * 16;
  #pragma unroll
  for (int r = 0; r < 4; r++) {
    int li = wave * 4 + r;
    int node = nodebase + li;
    if (node < NN) {
      int s = off[node], e = off[node + 1];
      for (int idx = s + lane; idx < e; idx += 64)
        atomicAdd(&sC[li][styp_s[idx]], norm_s[idx]);
      if (lane == 0) {
        float dd = dis[node];
        atomicAdd(&sC[li][types[node]], dd * dd);
      }
    }
  }
  __syncthreads();
  #pragma unroll
  for (int r = 0; r < 4; r++) {
    int li = wave * 4 + r;
    int node = nodebase + li;
    if (node < NN) {
      float2 acc = *(const float2*)&sB[lane * 2];
      #pragma unroll
      for (int tt = 0; tt < NT; tt++) {
        float c = sC[li][tt];
        float2 ev = *(const float2*)&sE[tt * D + lane * 2];
        acc.x = fmaf(c, ev.x, acc.x);
        acc.y = fmaf(c, ev.y, acc.y);
      }
      acc.x = fmaxf(acc.x, 0.f);
      acc.y = fmaxf(acc.y, 0.f);
      // uint index = lane (cols 2*lane, 2*lane+1) -> slab lane>>4, offset lane&15
      outbf[(size_t)(lane >> 4) * NN * 16 + (size_t)node * 16 + (lane & 15)] =
          pack2bf(acc.x, acc.y);
    }
  }
}

// ---------------- node GEMM via MFMA: xw = X @ W^T (bf16 slabs in/out) ----------------
// Block = 4 waves, each wave does 16 rows x 128 cols; K=128 in 4 mfma steps.

__global__ __launch_bounds__(256) void node_gemm_mfma(const uint* __restrict__ Aslab,
                                                      const uint* __restrict__ Wbf,
                                                      uint* __restrict__ outslab) {
  __shared__ ushort tile[4][16][136];  // per-wave 16x128 bf16, row padded to 136
  int w = threadIdx.x >> 6, lane = threadIdx.x & 63;
  int quad = lane >> 4;
  int m0 = blockIdx.x * 64 + w * 16;
  int mrow = m0 + (lane & 15);
  int arow = (mrow < NN) ? mrow : 0;
  // A frags: k-step ks covers cols 32ks..32ks+31 == slab ks; lane holds 8 bf16 at quad*8
  uint4 afr[4];
  #pragma unroll
  for (int ks = 0; ks < 4; ks++)
    afr[ks] = *(const uint4*)(Aslab + (size_t)ks * NN * 16 + (size_t)arow * 16 + quad * 4);
  f32x4 acc[8] = {};
  #pragma unroll
  for (int nt = 0; nt < 8; nt++) {
    int n = nt * 16 + (lane & 15);
    #pragma unroll
    for (int ks = 0; ks < 4; ks++) {
      union { uint4 u; bf16x8 v; } au, bu;
      au.u = afr[ks];
      bu.u = *(const uint4*)(Wbf + (size_t)n * 64 + ks * 16 + quad * 4);
      acc[nt] = __builtin_amdgcn_mfma_f32_16x16x32_bf16(au.v, bu.v, acc[nt], 0, 0, 0);
    }
  }
  // epilogue: C/D layout col=lane&15, row=quad*4+i -> LDS repack -> slab-major uint4 writes
  #pragma unroll
  for (int nt = 0; nt < 8; nt++)
    #pragma unroll
    for (int i = 0; i < 4; i++)
      tile[w][quad * 4 + i][nt * 16 + (lane & 15)] = (ushort)bf16rne(acc[nt][i]);
  // wave-synchronous LDS (per-wave tile; lgkmcnt orders write->read)
  #pragma unroll
  for (int rep = 0; rep < 4; rep++) {
    int r = rep * 4 + quad;
    int j = lane & 15;  // uint4 index 0..15 within row
    int node = m0 + r;
    if (node < NN) {
      uint4 v = *(const uint4*)&tile[w][r][j * 8];
      *(uint4*)(outslab + (size_t)(j >> 2) * NN * 16 + (size_t)node * 16 + (j & 3) * 4) = v;
    }
  }
}

// ---------------- sliced CSR aggregation: one dispatch per 32-col slab ----------------
// Wave = 1 node, 4 edges x 16 feature-lanes; slab (3.2 MB) stays L2-resident.

__global__ __launch_bounds__(256) void agg_slice(const uint* __restrict__ xwslab,
                                                 const int* __restrict__ off,
                                                 const int* __restrict__ src_s,
                                                 const float* __restrict__ norm_s,
                                                 const float* __restrict__ dis,
                                                 const float* __restrict__ bias,
                                                 int s, int relu,
                                                 uint* __restrict__ outbf,
                                                 float* __restrict__ outf) {
  int w = threadIdx.x >> 6, lane = threadIdx.x & 63;
  int node = blockIdx.x * 4 + w;
  if (node >= NN) return;
  int sub = lane >> 4, fl = lane & 15;
  float ax = 0.f, ay = 0.f;
  int b = off[node], e = off[node + 1];
  int idx = b + sub;
  for (; idx + 4 < e; idx += 8) {
    int s0 = src_s[idx];
    float n0 = norm_s[idx];
    int s1 = src_s[idx + 4];
    float n1 = norm_s[idx + 4];
    uint u0 = xwslab[(size_t)s0 * 16 + fl];
    uint u1 = xwslab[(size_t)s1 * 16 + fl];
    ax = fmaf(n0, bflo(u0), ax);
    ay = fmaf(n0, bfhi(u0), ay);
    ax = fmaf(n1, bflo(u1), ax);
    ay = fmaf(n1, bfhi(u1), ay);
  }
  if (idx < e) {
    int s0 = src_s[idx];
    float n0 = norm_s[idx];
    uint u0 = xwslab[(size_t)s0 * 16 + fl];
    ax = fmaf(n0, bflo(u0), ax);
    ay = fmaf(n0, bfhi(u0), ay);
  }
  ax += __shfl_xor(ax, 16);
  ay += __shfl_xor(ay, 16);
  ax += __shfl_xor(ax, 32);
  ay += __shfl_xor(ay, 32);
  if (sub == 0) {
    float dd = dis[node];
    dd *= dd;
    uint u = xwslab[(size_t)node * 16 + fl];
    ax = fmaf(dd, bflo(u), ax);
    ay = fmaf(dd, bfhi(u), ay);
    float2 bb = *(const float2*)(bias + s * 32 + fl * 2);
    ax += bb.x;
    ay += bb.y;
    if (relu) {
      ax = fmaxf(ax, 0.f);
      ay = fmaxf(ay, 0.f);
    }
    if (outbf) outbf[(size_t)node * 16 + fl] = pack2bf(ax, ay);
    else ((float2*)outf)[(size_t)node * 64 + s * 16 + fl] = make_float2(ax, ay);
  }
}

// ---------------- image GEMM via MFMA: xi = images @ W_img.T + b_img ----------------

__global__ void convA(const float* __restrict__ A, uint* __restrict__ Abf) {
  int idx = blockIdx.x * 256 + threadIdx.x;
  if (idx < 64 * IMG / 2) {
    float2 v = ((const float2*)A)[idx];
    Abf[idx] = pack2bf(v.x, v.y);
  }
}

__global__ __launch_bounds__(256) void img_mfma(const uint* __restrict__ Abf,
                                                const float* __restrict__ W,
                                                float* __restrict__ splitbuf) {
  int wv = threadIdx.x >> 6, lane = threadIdx.x & 63;
  int n = blockIdx.x * 64 + wv * 16 + (lane & 15);
  int kq = (lane >> 4) * 8;
  int k0 = blockIdx.y * 512 + kq;
  f32x4 acc[4] = {{0.f, 0.f, 0.f, 0.f}, {0.f, 0.f, 0.f, 0.f},
                  {0.f, 0.f, 0.f, 0.f}, {0.f, 0.f, 0.f, 0.f}};
  const float* wp = W + (size_t)n * IMG + k0;
  const uint* ap = Abf + (size_t)(lane & 15) * (IMG / 2) + k0 / 2;
  for (int ks = 0; ks < 512; ks += 32) {
    float4 w0 = *(const float4*)(wp + ks);
    float4 w1 = *(const float4*)(wp + ks + 4);
    union { uint4 u; bf16x8 v; } bu;
    bu.u.x = pack2bf(w0.x, w0.y);
    bu.u.y = pack2bf(w0.z, w0.w);
    bu.u.z = pack2bf(w1.x, w1.y);
    bu.u.w = pack2bf(w1.z, w1.w);
    #pragma unroll
    for (int mt = 0; mt < 4; mt++) {
      union { uint4 u; bf16x8 v; } au;
      au.u = *(const uint4*)(ap + (size_t)mt * 16 * (IMG / 2) + ks / 2);
      acc[mt] = __builtin_amdgcn_mfma_f32_16x16x32_bf16(au.v, bu.v, acc[mt], 0, 0, 0);
    }
  }
  #pragma unroll
  for (int mt = 0; mt < 4; mt++)
    #pragma unroll
    for (int i = 0; i < 4; i++) {
      int m = mt * 16 + (lane >> 4) * 4 + i;
      splitbuf[((size_t)blockIdx.y * 64 + m) * IMG + n] = acc[mt][i];
    }
}

__global__ __launch_bounds__(256) void img_reduce(const float* __restrict__ splitbuf,
                                                  const float* __restrict__ bias,
                                                  float* __restrict__ xi) {
  int idx = blockIdx.x * 256 + threadIdx.x;
  if (idx < 64 * IMG) {
    float acc = bias[idx & (IMG - 1)];
    #pragma unroll
    for (int s = 0; s < 8; s++) acc += splitbuf[(size_t)s * 64 * IMG + idx];
    xi[idx] = acc;
  }
}

// ---------------- small-M GEMM heads ----------------

__global__ __launch_bounds__(256) void biasinit(float* __restrict__ out,
                                                const float* __restrict__ bias, int N) {
  int idx = blockIdx.x * 256 + threadIdx.x;
  if (idx < 64 * N) out[idx] = bias[idx % N];
}

__global__ __launch_bounds__(256) void gemm64(const float* __restrict__ A,
                                              const float* __restrict__ W,
                                              float* __restrict__ out, int N, int K,
                                              int kChunk) {
  __shared__ float xs[16][68];
  __shared__ float ws[16][68];
  int t = threadIdx.x;
  int n0 = blockIdx.x * 64;
  int k0 = blockIdx.y * kChunk;
  int kEnd = min(K, k0 + kChunk);
  int tn = t & 15;
  int tm = t >> 4;
  float acc[4][4] = {};
  for (int kt = k0; kt < kEnd; kt += 16) {
    int kc = (t & 3) * 4;
    int rr = t >> 2;
    float4 va = *(const float4*)(A + (size_t)rr * K + kt + kc);
    xs[kc + 0][rr] = va.x; xs[kc + 1][rr] = va.y; xs[kc + 2][rr] = va.z; xs[kc + 3][rr] = va.w;
    float4 vw = *(const float4*)(W + (size_t)(n0 + rr) * K + kt + kc);
    ws[kc + 0][rr] = vw.x; ws[kc + 1][rr] = vw.y; ws[kc + 2][rr] = vw.z; ws[kc + 3][rr] = vw.w;
    __syncthreads();
    #pragma unroll
    for (int k = 0; k < 16; k++) {
      float4 xv = *(const float4*)&xs[k][tm * 4];
      float4 wv = *(const float4*)&ws[k][tn * 4];
      float xm[4] = {xv.x, xv.y, xv.z, xv.w};
      float wn[4] = {wv.x, wv.y, wv.z, wv.w};
      #pragma unroll
      for (int mi = 0; mi < 4; mi++)
        #pragma unroll
        for (int ni = 0; ni < 4; ni++)
          acc[mi][ni] = fmaf(xm[mi], wn[ni], acc[mi][ni]);
    }
    __syncthreads();
  }
  #pragma unroll
  for (int mi = 0; mi < 4; mi++)
    #pragma unroll
    for (int ni = 0; ni < 4; ni++)
      atomicAdd(&out[(size_t)(tm * 4 + mi) * N + n0 + tn * 4 + ni], acc[mi][ni]);
}

// ---------------- pooling + epilogue ----------------

__global__ void graph_bounds(const int* __restrict__ batch, int* __restrict__ goff) {
  int g = threadIdx.x;
  if (g <= NG) {
    int lo = 0, hi = NN;
    while (lo < hi) {
      int mid = (lo + hi) >> 1;
      if (batch[mid] < g) lo = mid + 1; else hi = mid;
    }
    goff[g] = lo;
  }
}

__global__ __launch_bounds__(128) void pool_partial(const float* __restrict__ xg,
                                                    const int* __restrict__ goff,
                                                    float* __restrict__ pooled) {
  int g = blockIdx.x;
  int chunk = blockIdx.y;
  int t = threadIdx.x;
  int s = goff[g], e = goff[g + 1];
  float acc = 0.f;
  for (int i = s + chunk; i < e; i += 8) acc += xg[(size_t)i * D + t];
  atomicAdd(&pooled[g * D + t], acc);
}

__global__ __launch_bounds__(128) void pool_finish(float* __restrict__ pooled,
                                                   const int* __restrict__ goff) {
  int g = blockIdx.x;
  int t = threadIdx.x;
  int c = goff[g + 1] - goff[g];
  pooled[g * D + t] /= fmaxf((float)c, 1.0f);
}

__global__ __launch_bounds__(256) void build_xcat(const float* __restrict__ xi,
                                                  const float* __restrict__ pooled,
                                                  float* __restrict__ xcat) {
  int idx = blockIdx.x * 256 + threadIdx.x;
  if (idx < 64 * 1056) {
    int r = idx / 1056;
    int c = idx % 1056;
    float4 v = (c < 1024) ? ((const float4*)xi)[r * 1024 + c]
                          : ((const float4*)pooled)[r * 32 + (c - 1024)];
    ((float4*)xcat)[idx] = v;
  }
}

__global__ __launch_bounds__(128) void normalize_rows(const float* __restrict__ oi_raw,
                                                      const float* __restrict__ oc_raw,
                                                      float* __restrict__ out) {
  int r = blockIdx.x;
  int t = threadIdx.x;
  const float* src = (r < 64) ? (oi_raw + r * D) : (oc_raw + (r - 64) * D);
  float v = src[t];
  __shared__ float red[128];
  red[t] = v * v;
  __syncthreads();
  for (int s = 64; s > 0; s >>= 1) {
    if (t < s) red[t] += red[t + s];
    __syncthreads();
  }
  out[r * D + t] = v / sqrtf(red[0]);
}

// ---------------- launch ----------------

extern "C" void kernel_launch(void* const* d_in, const int* in_sizes, int n_in,
                              void* d_out, int out_size, void* d_ws, size_t ws_size,
                              hipStream_t stream) {
  const float* images = (const float*)d_in[0];
  const int* node_types = (const int*)d_in[1];
  const int* erow = (const int*)d_in[2];
  const int* ecol = erow + NE;
  const float* eattr = (const float*)d_in[3];
  const int* batch = (const int*)d_in[4];
  const float* emb = (const float*)d_in[5];
  const float* W_img = (const float*)d_in[6];
  const float* b_img = (const float*)d_in[7];
  const float* W1 = (const float*)d_in[8];
  const float* b1 = (const float*)d_in[9];
  const float* W2 = (const float*)d_in[10];
  const float* b2 = (const float*)d_in[11];
  const float* W3 = (const float*)d_in[12];
  const float* b3 = (const float*)d_in[13];
  const float* Wi = (const float*)d_in[14];
  const float* bi = (const float*)d_in[15];
  const float* Wc = (const float*)d_in[16];
  const float* bc = (const float*)d_in[17];
  float* out = (float*)d_out;

  char* w = (char*)d_ws;
  auto alloc = [&](size_t bytes) -> void* {
    void* p = (void*)w;
    w += (bytes + 511) & ~(size_t)511;
    return p;
  };
  int* cnt_i = (int*)alloc(NN * 4);
  float* pooled = (float*)alloc(64 * D * 4);
  size_t zero_bytes = (size_t)(w - (char*)d_ws);  // cnt + pooled need zeroing
  int* csr_off = (int*)alloc((NN + 1) * 4);
  int* goff = (int*)alloc((NG + 1) * 4);
  int* scan_incl = (int*)alloc(NN * 4);
  int* scan_part = (int*)alloc(SCAN_BLOCKS * 4);
  int* slot = (int*)alloc((size_t)NE * 4);
  int* src_s = (int*)alloc((size_t)NE * 4);
  float* ew_s = (float*)alloc((size_t)NE * 4);
  float* norm_s = (float*)alloc((size_t)NE * 4);
  int* styp_s = (int*)alloc((size_t)NE * 4);
  float* dis = (float*)alloc(NN * 4);
  float* embW1 = (float*)alloc(NT * D * 4);
  uint* wbf2 = (uint*)alloc(D * 64 * 4);
  uint* wbf3 = (uint*)alloc(D * 64 * 4);
  float* bufA = (float*)alloc((size_t)NN * D * 4);    // X3 fp32 (for pooling)
  uint* bufX = (uint*)alloc((size_t)NN * D * 2);      // X bf16 slabs
  uint* bufB = (uint*)alloc((size_t)NN * D * 2);      // xw bf16 slabs
  float* xi = (float*)alloc((size_t)64 * IMG * 4);
  float* xcat = (float*)alloc((size_t)64 * (IMG + D) * 4);
  float* oi_raw = (float*)alloc(64 * D * 4);
  float* oc_raw = (float*)alloc(64 * D * 4);
  uint* imgAbf = (uint*)alloc((size_t)64 * IMG * 2);
  float* splitbuf = (float*)alloc((size_t)8 * 64 * IMG * 4);

  hipMemsetAsync(d_ws, 0, zero_bytes, stream);

  // graph preprocessing
  edge_slot<<<NE / 256, 256, 0, stream>>>(ecol, cnt_i, slot);
  scan_blocks<<<SCAN_BLOCKS, 256, 0, stream>>>(cnt_i, scan_incl, scan_part);
  scan_partials<<<1, 256, 0, stream>>>(scan_part, SCAN_BLOCKS);
  scan_apply<<<SCAN_BLOCKS, 256, 0, stream>>>(scan_incl, scan_part, csr_off);
  fill_scatter<<<NE / 256, 256, 0, stream>>>(erow, ecol, eattr, csr_off, slot, src_s, ew_s);
  deg_csr<<<(NN + 255) / 256, 256, 0, stream>>>(csr_off, ew_s, dis);
  norm_fill<<<(NN + 255) / 256, 256, 0, stream>>>(csr_off, src_s, ew_s, dis, node_types,
                                                  norm_s, styp_s);

  // layer 1 collapsed: X1 = relu(C @ (emb @ W1^T) + b1) -> bf16 slabs
  embw_k<<<(NT * D + 255) / 256, 256, 0, stream>>>(emb, W1, embW1);
  lay1_fused<<<(NN + 15) / 16, 256, 0, stream>>>(csr_off, styp_s, norm_s, dis, node_types,
                                                 embW1, b1, bufX);

  // layers 2 & 3: MFMA GEMM + sliced aggregation
  convW<<<(D * 64 + 255) / 256, 256, 0, stream>>>(W2, wbf2);
  convW<<<(D * 64 + 255) / 256, 256, 0, stream>>>(W3, wbf3);
  int gblk = (NN + 63) / 64;
  node_gemm_mfma<<<gblk, 256, 0, stream>>>(bufX, wbf2, bufB);
  for (int s = 0; s < 4; s++)
    agg_slice<<<(NN + 3) / 4, 256, 0, stream>>>(bufB + (size_t)s * NN * 16, csr_off, src_s,
                                                norm_s, dis, b2, s, 1,
                                                bufX + (size_t)s * NN * 16, (float*)0);
  node_gemm_mfma<<<gblk, 256, 0, stream>>>(bufX, wbf3, bufB);
  for (int s = 0; s < 4; s++)
    agg_slice<<<(NN + 3) / 4, 256, 0, stream>>>(bufB + (size_t)s * NN * 16, csr_off, src_s,
                                                norm_s, dis, b3, s, 0, (uint*)0, bufA);

  // pooling
  graph_bounds<<<1, 128, 0, stream>>>(batch, goff);
  {
    dim3 g(NG, 8);
    pool_partial<<<g, 128, 0, stream>>>(bufA, goff, pooled);
  }
  pool_finish<<<NG, 128, 0, stream>>>(pooled, goff);

  // image path: xi = images @ W_img.T + b_img  (bf16 MFMA, split-k)
  convA<<<(64 * IMG / 2 + 255) / 256, 256, 0, stream>>>(images, imgAbf);
  {
    dim3 g(IMG / 64, 8);
    img_mfma<<<g, 256, 0, stream>>>(imgAbf, W_img, splitbuf);
  }
  img_reduce<<<(64 * IMG + 255) / 256, 256, 0, stream>>>(splitbuf, b_img, xi);

  // oi = normalize(xi @ Wi.T + bi)
  biasinit<<<(64 * D + 255) / 256, 256, 0, stream>>>(oi_raw, bi, D);
  {
    dim3 g(D / 64, 32);
    gemm64<<<g, 256, 0, stream>>>(xi, Wi, oi_raw, D, IMG, 128);
  }
  // oc = normalize(concat(xi, pooled) @ Wc.T + bc)
  build_xcat<<<(64 * 1056 + 255) / 256, 256, 0, stream>>>(xi, pooled, xcat);
  biasinit<<<(64 * D + 255) / 256, 256, 0, stream>>>(oc_raw, bc, D);
  {
    dim3 g(D / 64, 24);
    gemm64<<<g, 256, 0, stream>>>(xcat, Wc, oc_raw, D, IMG + D, 176);
  }
  normalize_rows<<<128, 128, 0, stream>>>(oi_raw, oc_raw, out);
}

// Round 8
// 489.552 us; speedup vs baseline: 1.2032x; 1.2032x over previous
//
#include <hip/hip_runtime.h>
#include <math.h>

#define NN 50000
#define NE 800000
#define NG 64
#define D 128
#define IMG 4096
#define NT 30
#define SCAN_BLOCKS ((NN + 255) / 256)

typedef unsigned int uint;
typedef unsigned short ushort;
typedef __attribute__((ext_vector_type(8))) __bf16 bf16x8;
typedef __attribute__((ext_vector_type(4))) float f32x4;

// bf16 helpers (bit-level, RNE pack / shift unpack)
__device__ __forceinline__ uint bf16rne(float f) {
  uint h = __float_as_uint(f);
  return (h + 0x7fffu + ((h >> 16) & 1u)) >> 16;
}
__device__ __forceinline__ uint pack2bf(float a, float b) {
  return bf16rne(a) | (bf16rne(b) << 16);
}
__device__ __forceinline__ float bflo(uint u) { return __uint_as_float(u << 16); }
__device__ __forceinline__ float bfhi(uint u) { return __uint_as_float(u & 0xffff0000u); }

// X / xw bf16 storage: ROW-MAJOR, 64 uints (128 bf16) per node row.

// ---------------- graph preprocessing ----------------

__global__ void edge_slot(const int* __restrict__ col, int* __restrict__ cnt,
                          int* __restrict__ slot) {
  int e = blockIdx.x * 256 + threadIdx.x;
  if (e < NE) {
    int c = col[e];
    slot[e] = atomicAdd(&cnt[c], 1);
  }
}

__global__ __launch_bounds__(256) void scan_blocks(const int* __restrict__ cnt,
                                                   int* __restrict__ incl,
                                                   int* __restrict__ partial) {
  __shared__ int sd[256];
  int t = threadIdx.x;
  int i = blockIdx.x * 256 + t;
  int v = (i < NN) ? cnt[i] : 0;
  sd[t] = v;
  __syncthreads();
  #pragma unroll
  for (int s = 1; s < 256; s <<= 1) {
    int add = (t >= s) ? sd[t - s] : 0;
    __syncthreads();
    sd[t] += add;
    __syncthreads();
  }
  if (i < NN) incl[i] = sd[t];
  if (t == 255) partial[blockIdx.x] = sd[255];
}

__global__ __launch_bounds__(256) void scan_partials(int* __restrict__ partial, int nb) {
  __shared__ int sd[256];
  int t = threadIdx.x;
  int v = (t < nb) ? partial[t] : 0;
  sd[t] = v;
  __syncthreads();
  #pragma unroll
  for (int s = 1; s < 256; s <<= 1) {
    int add = (t >= s) ? sd[t - s] : 0;
    __syncthreads();
    sd[t] += add;
    __syncthreads();
  }
  if (t < nb) partial[t] = (t == 0) ? 0 : sd[t - 1];
}

__global__ __launch_bounds__(256) void scan_apply(const int* __restrict__ incl,
                                                  const int* __restrict__ partial,
                                                  int* __restrict__ off) {
  int i = blockIdx.x * 256 + threadIdx.x;
  if (i < NN) off[i + 1] = incl[i] + partial[blockIdx.x];
  if (i == 0) off[0] = 0;
}

__global__ void fill_scatter(const int* __restrict__ row, const int* __restrict__ col,
                             const float* __restrict__ ew, const int* __restrict__ off,
                             const int* __restrict__ slot, int* __restrict__ src_s,
                             float* __restrict__ ew_s) {
  int e = blockIdx.x * 256 + threadIdx.x;
  if (e < NE) {
    int idx = off[col[e]] + slot[e];
    src_s[idx] = row[e];
    ew_s[idx] = ew[e];
  }
}

__global__ void deg_csr(const int* __restrict__ off, const float* __restrict__ ew_s,
                        float* __restrict__ dis) {
  int i = blockIdx.x * 256 + threadIdx.x;
  if (i < NN) {
    int s = off[i], e = off[i + 1];
    float acc = 0.f;
    for (int j = s; j < e; j++) acc += ew_s[j];
    dis[i] = 1.0f / sqrtf(acc + 1.0f);
  }
}

__global__ void norm_fill(const int* __restrict__ off, const int* __restrict__ src_s,
                          const float* __restrict__ ew_s, const float* __restrict__ dis,
                          const int* __restrict__ types, float* __restrict__ norm_s,
                          int* __restrict__ styp_s) {
  int i = blockIdx.x * 256 + threadIdx.x;
  if (i < NN) {
    int s = off[i], e = off[i + 1];
    float dc = dis[i];
    for (int j = s; j < e; j++) {
      int sv = src_s[j];
      norm_s[j] = dis[sv] * ew_s[j] * dc;
      styp_s[j] = types[sv];
    }
  }
}

// embW[t][n] = sum_k emb[t][k] * W1[n][k]   (30 x 128)
__global__ void embw_k(const float* __restrict__ emb, const float* __restrict__ W,
                       float* __restrict__ embW) {
  int tid = blockIdx.x * 256 + threadIdx.x;
  if (tid < NT * D) {
    int t = tid >> 7, n = tid & 127;
    const float* e = emb + (size_t)t * D;
    const float* w = W + (size_t)n * D;
    float acc = 0.f;
    for (int k = 0; k < D; k += 4) {
      float4 ev = *(const float4*)(e + k);
      float4 wv = *(const float4*)(w + k);
      acc += ev.x * wv.x + ev.y * wv.y + ev.z * wv.z + ev.w * wv.w;
    }
    embW[tid] = acc;
  }
}

// fp32 W (128x128, row-major k-contig) -> bf16 packed (64 uints per row)
__global__ void convW(const float* __restrict__ W, uint* __restrict__ Wbf) {
  int idx = blockIdx.x * 256 + threadIdx.x;  // 128*64
  if (idx < D * 64) {
    float2 v = ((const float2*)W)[idx];
    Wbf[idx] = pack2bf(v.x, v.y);
  }
}

// ---------------- layer 1 fused: X1 = relu(C @ embW1 + b1), bf16 row-major out ----------------

__global__ __launch_bounds__(256) void lay1_fused(const int* __restrict__ off,
                                                  const int* __restrict__ styp_s,
                                                  const float* __restrict__ norm_s,
                                                  const float* __restrict__ dis,
                                                  const int* __restrict__ types,
                                                  const float* __restrict__ embW,
                                                  const float* __restrict__ b1,
                                                  uint* __restrict__ outbf) {
  __shared__ float sE[NT * D];
  __shared__ float sC[16][32];
  __shared__ float sB[D];
  int t = threadIdx.x;
  for (int i = t; i < NT * D; i += 256) sE[i] = embW[i];
  if (t < D) sB[t] = b1[t];
  for (int i = t; i < 16 * 32; i += 256) ((float*)sC)[i] = 0.f;
  __syncthreads();
  int wave = t >> 6, lane = t & 63;
  int nodebase = blockIdx.x * 16;
  #pragma unroll
  for (int r = 0; r < 4; r++) {
    int li = wave * 4 + r;
    int node = nodebase + li;
    if (node < NN) {
      int s = off[node], e = off[node + 1];
      for (int idx = s + lane; idx < e; idx += 64)
        atomicAdd(&sC[li][styp_s[idx]], norm_s[idx]);
      if (lane == 0) {
        float dd = dis[node];
        atomicAdd(&sC[li][types[node]], dd * dd);
      }
    }
  }
  __syncthreads();
  #pragma unroll
  for (int r = 0; r < 4; r++) {
    int li = wave * 4 + r;
    int node = nodebase + li;
    if (node < NN) {
      float2 acc = *(const float2*)&sB[lane * 2];
      #pragma unroll
      for (int tt = 0; tt < NT; tt++) {
        float c = sC[li][tt];
        float2 ev = *(const float2*)&sE[tt * D + lane * 2];
        acc.x = fmaf(c, ev.x, acc.x);
        acc.y = fmaf(c, ev.y, acc.y);
      }
      acc.x = fmaxf(acc.x, 0.f);
      acc.y = fmaxf(acc.y, 0.f);
      outbf[(size_t)node * 64 + lane] = pack2bf(acc.x, acc.y);
    }
  }
}

// ---------------- node GEMM via MFMA: xw = X @ W^T (bf16 row-major in/out) ----------------
// Block = 4 waves, each wave does 16 rows x 128 cols; K=128 in 4 mfma steps.

__global__ __launch_bounds__(256) void node_gemm_mfma(const uint* __restrict__ Abf,
                                                      const uint* __restrict__ Wbf,
                                                      uint* __restrict__ outbf) {
  __shared__ ushort tile[4][16][136];  // per-wave 16x128 bf16, row padded
  int w = threadIdx.x >> 6, lane = threadIdx.x & 63;
  int quad = lane >> 4;
  int m0 = blockIdx.x * 64 + w * 16;
  int mrow = m0 + (lane & 15);
  int arow = (mrow < NN) ? mrow : 0;
  // A frag for k-step ks: lane holds 8 bf16 at row arow, cols 32ks + quad*8
  uint4 afr[4];
  #pragma unroll
  for (int ks = 0; ks < 4; ks++)
    afr[ks] = *(const uint4*)(Abf + (size_t)arow * 64 + ks * 16 + quad * 4);
  f32x4 acc[8] = {};
  #pragma unroll
  for (int nt = 0; nt < 8; nt++) {
    int n = nt * 16 + (lane & 15);
    #pragma unroll
    for (int ks = 0; ks < 4; ks++) {
      union { uint4 u; bf16x8 v; } au, bu;
      au.u = afr[ks];
      bu.u = *(const uint4*)(Wbf + (size_t)n * 64 + ks * 16 + quad * 4);
      acc[nt] = __builtin_amdgcn_mfma_f32_16x16x32_bf16(au.v, bu.v, acc[nt], 0, 0, 0);
    }
  }
  // epilogue: C/D col=lane&15 (n in tile), row=quad*4+i -> LDS repack -> row-major uint4
  #pragma unroll
  for (int nt = 0; nt < 8; nt++)
    #pragma unroll
    for (int i = 0; i < 4; i++)
      tile[w][quad * 4 + i][nt * 16 + (lane & 15)] = (ushort)bf16rne(acc[nt][i]);
  __builtin_amdgcn_s_waitcnt(0);  // wave-local LDS ordering (per-wave tile)
  #pragma unroll
  for (int rep = 0; rep < 4; rep++) {
    int r = rep * 4 + quad;
    int j = lane & 15;
    int node = m0 + r;
    if (node < NN) {
      uint4 v = *(const uint4*)&tile[w][r][j * 8];
      *(uint4*)(outbf + (size_t)node * 64 + j * 4) = v;
    }
  }
}

// ---------------- CSR aggregation: one wave per node, bf16 gather, 8x MLP ----------------
// Dual output: bf16 row-major (layers 1->2) or fp32 (final layer, for pooling).

__global__ __launch_bounds__(256) void aggregate(const uint* __restrict__ xw,
                                                 const int* __restrict__ off,
                                                 const int* __restrict__ src_s,
                                                 const float* __restrict__ norm_s,
                                                 const float* __restrict__ dis,
                                                 const float* __restrict__ bias, int relu,
                                                 uint* __restrict__ outbf,
                                                 float* __restrict__ outf) {
  int wave = threadIdx.x >> 6;
  int lane = threadIdx.x & 63;
  int node = blockIdx.x * 4 + wave;
  if (node >= NN) return;
  float accx = 0.f, accy = 0.f;
  int s = off[node], e = off[node + 1];
  int idx = s;
  int astart = (s + 3) & ~3;
  if (astart > e) astart = e;
  for (; idx < astart; idx++) {
    int src = src_s[idx];
    float nm = norm_s[idx];
    uint u = xw[(size_t)src * 64 + lane];
    accx = fmaf(nm, bflo(u), accx);
    accy = fmaf(nm, bfhi(u), accy);
  }
  for (; idx + 8 <= e; idx += 8) {
    int4 sa = *(const int4*)(src_s + idx);
    int4 sb = *(const int4*)(src_s + idx + 4);
    float4 na = *(const float4*)(norm_s + idx);
    float4 nb = *(const float4*)(norm_s + idx + 4);
    uint u0 = xw[(size_t)sa.x * 64 + lane];
    uint u1 = xw[(size_t)sa.y * 64 + lane];
    uint u2 = xw[(size_t)sa.z * 64 + lane];
    uint u3 = xw[(size_t)sa.w * 64 + lane];
    uint u4 = xw[(size_t)sb.x * 64 + lane];
    uint u5 = xw[(size_t)sb.y * 64 + lane];
    uint u6 = xw[(size_t)sb.z * 64 + lane];
    uint u7 = xw[(size_t)sb.w * 64 + lane];
    accx = fmaf(na.x, bflo(u0), accx);
    accy = fmaf(na.x, bfhi(u0), accy);
    accx = fmaf(na.y, bflo(u1), accx);
    accy = fmaf(na.y, bfhi(u1), accy);
    accx = fmaf(na.z, bflo(u2), accx);
    accy = fmaf(na.z, bfhi(u2), accy);
    accx = fmaf(na.w, bflo(u3), accx);
    accy = fmaf(na.w, bfhi(u3), accy);
    accx = fmaf(nb.x, bflo(u4), accx);
    accy = fmaf(nb.x, bfhi(u4), accy);
    accx = fmaf(nb.y, bflo(u5), accx);
    accy = fmaf(nb.y, bfhi(u5), accy);
    accx = fmaf(nb.z, bflo(u6), accx);
    accy = fmaf(nb.z, bfhi(u6), accy);
    accx = fmaf(nb.w, bflo(u7), accx);
    accy = fmaf(nb.w, bfhi(u7), accy);
  }
  for (; idx + 4 <= e; idx += 4) {
    int4 sr = *(const int4*)(src_s + idx);
    float4 nm = *(const float4*)(norm_s + idx);
    uint u0 = xw[(size_t)sr.x * 64 + lane];
    uint u1 = xw[(size_t)sr.y * 64 + lane];
    uint u2 = xw[(size_t)sr.z * 64 + lane];
    uint u3 = xw[(size_t)sr.w * 64 + lane];
    accx = fmaf(nm.x, bflo(u0), accx);
    accy = fmaf(nm.x, bfhi(u0), accy);
    accx = fmaf(nm.y, bflo(u1), accx);
    accy = fmaf(nm.y, bfhi(u1), accy);
    accx = fmaf(nm.z, bflo(u2), accx);
    accy = fmaf(nm.z, bfhi(u2), accy);
    accx = fmaf(nm.w, bflo(u3), accx);
    accy = fmaf(nm.w, bfhi(u3), accy);
  }
  for (; idx < e; idx++) {
    int src = src_s[idx];
    float nm = norm_s[idx];
    uint u = xw[(size_t)src * 64 + lane];
    accx = fmaf(nm, bflo(u), accx);
    accy = fmaf(nm, bfhi(u), accy);
  }
  // self-loop
  float dd = dis[node];
  dd = dd * dd;
  {
    uint u = xw[(size_t)node * 64 + lane];
    accx = fmaf(dd, bflo(u), accx);
    accy = fmaf(dd, bfhi(u), accy);
  }
  float2 b = ((const float2*)bias)[lane];
  accx += b.x;
  accy += b.y;
  if (relu) {
    accx = fmaxf(accx, 0.f);
    accy = fmaxf(accy, 0.f);
  }
  if (outbf) outbf[(size_t)node * 64 + lane] = pack2bf(accx, accy);
  else ((float2*)outf)[(size_t)node * 64 + lane] = make_float2(accx, accy);
}

// ---------------- image GEMM via MFMA: xi = images @ W_img.T + b_img ----------------

__global__ void convA(const float* __restrict__ A, uint* __restrict__ Abf) {
  int idx = blockIdx.x * 256 + threadIdx.x;
  if (idx < 64 * IMG / 2) {
    float2 v = ((const float2*)A)[idx];
    Abf[idx] = pack2bf(v.x, v.y);
  }
}

__global__ __launch_bounds__(256) void img_mfma(const uint* __restrict__ Abf,
                                                const float* __restrict__ W,
                                                float* __restrict__ splitbuf) {
  int wv = threadIdx.x >> 6, lane = threadIdx.x & 63;
  int n = blockIdx.x * 64 + wv * 16 + (lane & 15);
  int kq = (lane >> 4) * 8;
  int k0 = blockIdx.y * 512 + kq;
  f32x4 acc[4] = {{0.f, 0.f, 0.f, 0.f}, {0.f, 0.f, 0.f, 0.f},
                  {0.f, 0.f, 0.f, 0.f}, {0.f, 0.f, 0.f, 0.f}};
  const float* wp = W + (size_t)n * IMG + k0;
  const uint* ap = Abf + (size_t)(lane & 15) * (IMG / 2) + k0 / 2;
  for (int ks = 0; ks < 512; ks += 32) {
    float4 w0 = *(const float4*)(wp + ks);
    float4 w1 = *(const float4*)(wp + ks + 4);
    union { uint4 u; bf16x8 v; } bu;
    bu.u.x = pack2bf(w0.x, w0.y);
    bu.u.y = pack2bf(w0.z, w0.w);
    bu.u.z = pack2bf(w1.x, w1.y);
    bu.u.w = pack2bf(w1.z, w1.w);
    #pragma unroll
    for (int mt = 0; mt < 4; mt++) {
      union { uint4 u; bf16x8 v; } au;
      au.u = *(const uint4*)(ap + (size_t)mt * 16 * (IMG / 2) + ks / 2);
      acc[mt] = __builtin_amdgcn_mfma_f32_16x16x32_bf16(au.v, bu.v, acc[mt], 0, 0, 0);
    }
  }
  #pragma unroll
  for (int mt = 0; mt < 4; mt++)
    #pragma unroll
    for (int i = 0; i < 4; i++) {
      int m = mt * 16 + (lane >> 4) * 4 + i;
      splitbuf[((size_t)blockIdx.y * 64 + m) * IMG + n] = acc[mt][i];
    }
}

__global__ __launch_bounds__(256) void img_reduce(const float* __restrict__ splitbuf,
                                                  const float* __restrict__ bias,
                                                  float* __restrict__ xi) {
  int idx = blockIdx.x * 256 + threadIdx.x;
  if (idx < 64 * IMG) {
    float acc = bias[idx & (IMG - 1)];
    #pragma unroll
    for (int s = 0; s < 8; s++) acc += splitbuf[(size_t)s * 64 * IMG + idx];
    xi[idx] = acc;
  }
}

// ---------------- small-M GEMM heads ----------------

__global__ __launch_bounds__(256) void biasinit(float* __restrict__ out,
                                                const float* __restrict__ bias, int N) {
  int idx = blockIdx.x * 256 + threadIdx.x;
  if (idx < 64 * N) out[idx] = bias[idx % N];
}

__global__ __launch_bounds__(256) void gemm64(const float* __restrict__ A,
                                              const float* __restrict__ W,
                                              float* __restrict__ out, int N, int K,
                                              int kChunk) {
  __shared__ float xs[16][68];
  __shared__ float ws[16][68];
  int t = threadIdx.x;
  int n0 = blockIdx.x * 64;
  int k0 = blockIdx.y * kChunk;
  int kEnd = min(K, k0 + kChunk);
  int tn = t & 15;
  int tm = t >> 4;
  float acc[4][4] = {};
  for (int kt = k0; kt < kEnd; kt += 16) {
    int kc = (t & 3) * 4;
    int rr = t >> 2;
    float4 va = *(const float4*)(A + (size_t)rr * K + kt + kc);
    xs[kc + 0][rr] = va.x; xs[kc + 1][rr] = va.y; xs[kc + 2][rr] = va.z; xs[kc + 3][rr] = va.w;
    float4 vw = *(const float4*)(W + (size_t)(n0 + rr) * K + kt + kc);
    ws[kc + 0][rr] = vw.x; ws[kc + 1][rr] = vw.y; ws[kc + 2][rr] = vw.z; ws[kc + 3][rr] = vw.w;
    __syncthreads();
    #pragma unroll
    for (int k = 0; k < 16; k++) {
      float4 xv = *(const float4*)&xs[k][tm * 4];
      float4 wv = *(const float4*)&ws[k][tn * 4];
      float xm[4] = {xv.x, xv.y, xv.z, xv.w};
      float wn[4] = {wv.x, wv.y, wv.z, wv.w};
      #pragma unroll
      for (int mi = 0; mi < 4; mi++)
        #pragma unroll
        for (int ni = 0; ni < 4; ni++)
          acc[mi][ni] = fmaf(xm[mi], wn[ni], acc[mi][ni]);
    }
    __syncthreads();
  }
  #pragma unroll
  for (int mi = 0; mi < 4; mi++)
    #pragma unroll
    for (int ni = 0; ni < 4; ni++)
      atomicAdd(&out[(size_t)(tm * 4 + mi) * N + n0 + tn * 4 + ni], acc[mi][ni]);
}

// ---------------- pooling + epilogue ----------------

__global__ void graph_bounds(const int* __restrict__ batch, int* __restrict__ goff) {
  int g = threadIdx.x;
  if (g <= NG) {
    int lo = 0, hi = NN;
    while (lo < hi) {
      int mid = (lo + hi) >> 1;
      if (batch[mid] < g) lo = mid + 1; else hi = mid;
    }
    goff[g] = lo;
  }
}

__global__ __launch_bounds__(128) void pool_partial(const float* __restrict__ xg,
                                                    const int* __restrict__ goff,
                                                    float* __restrict__ pooled) {
  int g = blockIdx.x;
  int chunk = blockIdx.y;
  int t = threadIdx.x;
  int s = goff[g], e = goff[g + 1];
  float acc = 0.f;
  for (int i = s + chunk; i < e; i += 8) acc += xg[(size_t)i * D + t];
  atomicAdd(&pooled[g * D + t], acc);
}

__global__ __launch_bounds__(128) void pool_finish(float* __restrict__ pooled,
                                                   const int* __restrict__ goff) {
  int g = blockIdx.x;
  int t = threadIdx.x;
  int c = goff[g + 1] - goff[g];
  pooled[g * D + t] /= fmaxf((float)c, 1.0f);
}

__global__ __launch_bounds__(256) void build_xcat(const float* __restrict__ xi,
                                                  const float* __restrict__ pooled,
                                                  float* __restrict__ xcat) {
  int idx = blockIdx.x * 256 + threadIdx.x;
  if (idx < 64 * 1056) {
    int r = idx / 1056;
    int c = idx % 1056;
    float4 v = (c < 1024) ? ((const float4*)xi)[r * 1024 + c]
                          : ((const float4*)pooled)[r * 32 + (c - 1024)];
    ((float4*)xcat)[idx] = v;
  }
}

__global__ __launch_bounds__(128) void normalize_rows(const float* __restrict__ oi_raw,
                                                      const float* __restrict__ oc_raw,
                                                      float* __restrict__ out) {
  int r = blockIdx.x;
  int t = threadIdx.x;
  const float* src = (r < 64) ? (oi_raw + r * D) : (oc_raw + (r - 64) * D);
  float v = src[t];
  __shared__ float red[128];
  red[t] = v * v;
  __syncthreads();
  for (int s = 64; s > 0; s >>= 1) {
    if (t < s) red[t] += red[t + s];
    __syncthreads();
  }
  out[r * D + t] = v / sqrtf(red[0]);
}

// ---------------- launch ----------------

extern "C" void kernel_launch(void* const* d_in, const int* in_sizes, int n_in,
                              void* d_out, int out_size, void* d_ws, size_t ws_size,
                              hipStream_t stream) {
  const float* images = (const float*)d_in[0];
  const int* node_types = (const int*)d_in[1];
  const int* erow = (const int*)d_in[2];
  const int* ecol = erow + NE;
  const float* eattr = (const float*)d_in[3];
  const int* batch = (const int*)d_in[4];
  const float* emb = (const float*)d_in[5];
  const float* W_img = (const float*)d_in[6];
  const float* b_img = (const float*)d_in[7];
  const float* W1 = (const float*)d_in[8];
  const float* b1 = (const float*)d_in[9];
  const float* W2 = (const float*)d_in[10];
  const float* b2 = (const float*)d_in[11];
  const float* W3 = (const float*)d_in[12];
  const float* b3 = (const float*)d_in[13];
  const float* Wi = (const float*)d_in[14];
  const float* bi = (const float*)d_in[15];
  const float* Wc = (const float*)d_in[16];
  const float* bc = (const float*)d_in[17];
  float* out = (float*)d_out;

  char* w = (char*)d_ws;
  auto alloc = [&](size_t bytes) -> void* {
    void* p = (void*)w;
    w += (bytes + 511) & ~(size_t)511;
    return p;
  };
  int* cnt_i = (int*)alloc(NN * 4);
  float* pooled = (float*)alloc(64 * D * 4);
  size_t zero_bytes = (size_t)(w - (char*)d_ws);  // cnt + pooled need zeroing
  int* csr_off = (int*)alloc((NN + 1) * 4);
  int* goff = (int*)alloc((NG + 1) * 4);
  int* scan_incl = (int*)alloc(NN * 4);
  int* scan_part = (int*)alloc(SCAN_BLOCKS * 4);
  int* slot = (int*)alloc((size_t)NE * 4);
  int* src_s = (int*)alloc((size_t)NE * 4);
  float* ew_s = (float*)alloc((size_t)NE * 4);
  float* norm_s = (float*)alloc((size_t)NE * 4);
  int* styp_s = (int*)alloc((size_t)NE * 4);
  float* dis = (float*)alloc(NN * 4);
  float* embW1 = (float*)alloc(NT * D * 4);
  uint* wbf2 = (uint*)alloc(D * 64 * 4);
  uint* wbf3 = (uint*)alloc(D * 64 * 4);
  float* bufA = (float*)alloc((size_t)NN * D * 4);    // X3 fp32 (for pooling)
  uint* bufX = (uint*)alloc((size_t)NN * D * 2);      // X bf16 rows
  uint* bufB = (uint*)alloc((size_t)NN * D * 2);      // xw bf16 rows
  float* xi = (float*)alloc((size_t)64 * IMG * 4);
  float* xcat = (float*)alloc((size_t)64 * (IMG + D) * 4);
  float* oi_raw = (float*)alloc(64 * D * 4);
  float* oc_raw = (float*)alloc(64 * D * 4);
  uint* imgAbf = (uint*)alloc((size_t)64 * IMG * 2);
  float* splitbuf = (float*)alloc((size_t)8 * 64 * IMG * 4);

  hipMemsetAsync(d_ws, 0, zero_bytes, stream);

  // graph preprocessing
  edge_slot<<<NE / 256, 256, 0, stream>>>(ecol, cnt_i, slot);
  scan_blocks<<<SCAN_BLOCKS, 256, 0, stream>>>(cnt_i, scan_incl, scan_part);
  scan_partials<<<1, 256, 0, stream>>>(scan_part, SCAN_BLOCKS);
  scan_apply<<<SCAN_BLOCKS, 256, 0, stream>>>(scan_incl, scan_part, csr_off);
  fill_scatter<<<NE / 256, 256, 0, stream>>>(erow, ecol, eattr, csr_off, slot, src_s, ew_s);
  deg_csr<<<(NN + 255) / 256, 256, 0, stream>>>(csr_off, ew_s, dis);
  norm_fill<<<(NN + 255) / 256, 256, 0, stream>>>(csr_off, src_s, ew_s, dis, node_types,
                                                  norm_s, styp_s);

  // layer 1 collapsed: X1 = relu(C @ (emb @ W1^T) + b1) -> bf16 rows
  embw_k<<<(NT * D + 255) / 256, 256, 0, stream>>>(emb, W1, embW1);
  lay1_fused<<<(NN + 15) / 16, 256, 0, stream>>>(csr_off, styp_s, norm_s, dis, node_types,
                                                 embW1, b1, bufX);

  // layers 2 & 3: MFMA GEMM + monolithic aggregation
  convW<<<(D * 64 + 255) / 256, 256, 0, stream>>>(W2, wbf2);
  convW<<<(D * 64 + 255) / 256, 256, 0, stream>>>(W3, wbf3);
  int gblk = (NN + 63) / 64;
  node_gemm_mfma<<<gblk, 256, 0, stream>>>(bufX, wbf2, bufB);
  aggregate<<<(NN + 3) / 4, 256, 0, stream>>>(bufB, csr_off, src_s, norm_s, dis, b2, 1,
                                              bufX, (float*)0);
  node_gemm_mfma<<<gblk, 256, 0, stream>>>(bufX, wbf3, bufB);
  aggregate<<<(NN + 3) / 4, 256, 0, stream>>>(bufB, csr_off, src_s, norm_s, dis, b3, 0,
                                              (uint*)0, bufA);

  // pooling
  graph_bounds<<<1, 128, 0, stream>>>(batch, goff);
  {
    dim3 g(NG, 8);
    pool_partial<<<g, 128, 0, stream>>>(bufA, goff, pooled);
  }
  pool_finish<<<NG, 128, 0, stream>>>(pooled, goff);

  // image path: xi = images @ W_img.T + b_img  (bf16 MFMA, split-k)
  convA<<<(64 * IMG / 2 + 255) / 256, 256, 0, stream>>>(images, imgAbf);
  {
    dim3 g(IMG / 64, 8);
    img_mfma<<<g, 256, 0, stream>>>(imgAbf, W_img, splitbuf);
  }
  img_reduce<<<(64 * IMG + 255) / 256, 256, 0, stream>>>(splitbuf, b_img, xi);

  // oi = normalize(xi @ Wi.T + bi)
  biasinit<<<(64 * D + 255) / 256, 256, 0, stream>>>(oi_raw, bi, D);
  {
    dim3 g(D / 64, 32);
    gemm64<<<g, 256, 0, stream>>>(xi, Wi, oi_raw, D, IMG, 128);
  }
  // oc = normalize(concat(xi, pooled) @ Wc.T + bc)
  build_xcat<<<(64 * 1056 + 255) / 256, 256, 0, stream>>>(xi, pooled, xcat);
  biasinit<<<(64 * D + 255) / 256, 256, 0, stream>>>(oc_raw, bc, D);
  {
    dim3 g(D / 64, 24);
    gemm64<<<g, 256, 0, stream>>>(xcat, Wc, oc_raw, D, IMG + D, 176);
  }
  normalize_rows<<<128, 128, 0, stream>>>(oi_raw, oc_raw, out);
}